// Round 7
// baseline (167.921 us; speedup 1.0000x reference)
//
#include <hip/hip_runtime.h>
#include <hip/hip_bf16.h>

#define NL 2048   // languages
#define DE 64     // embedding dim
#define VV 2048   // vocab
#define BT 32     // pair tile (32x32)
#define NT (NL / BT)          // 64 tiles per side
#define NBLK (NT * (NT + 1) / 2)  // 2080 triangular tiles
#define STA 68    // Ei stride: 68%32==4 -> <=4-way on writes, 2-way on reads (cheap)
#define STB 36    // Ejt stride: 36%32==4 -> conflict-free/2-way

// ws layout (NO memset needed — prep initializes everything):
// [0:8)      double wsum      (zeroed by prep block 0)
// [8:12)     uint   wcnt      (zeroed by prep block 0)
// [12:16)    uint   done      (zeroed by prep block 0)
// [16:1040)  float  pmax[256] (plain stores by prep max-blocks)
// [1040:9232)   int perm[2048]
// [9232:17424)  int sids[2048]

// Blocks 0..255: block-local max over map_dist slice -> pmax[b] (plain store).
// Block 256: counting-sort 2048 ids in LDS. Block 0 also zeroes the scalars.
__global__ __launch_bounds__(1024) void prep_kernel(const int* __restrict__ ids,
                                                    const float4* __restrict__ m4,
                                                    float* __restrict__ pmax,
                                                    int* __restrict__ perm,
                                                    int* __restrict__ sids,
                                                    double* __restrict__ wsum,
                                                    unsigned* __restrict__ wcnt,
                                                    unsigned* __restrict__ done) {
    const int t = threadIdx.x;
    const int lane = t & 63, wave = t >> 6;
    const int b = blockIdx.x;

    if (b < 256) {
        if (b == 0 && t == 0) { *wsum = 0.0; *wcnt = 0u; *done = 0u; }
        const float4* p = m4 + (size_t)b * 4096;
        const float4 x0 = p[t], x1 = p[t + 1024], x2 = p[t + 2048], x3 = p[t + 3072];
        float v = fmaxf(fmaxf(fmaxf(x0.x, x0.y), fmaxf(x0.z, x0.w)),
                        fmaxf(fmaxf(x1.x, x1.y), fmaxf(x1.z, x1.w)));
        v = fmaxf(v, fmaxf(fmaxf(x2.x, x2.y), fmaxf(x2.z, x2.w)));
        v = fmaxf(v, fmaxf(fmaxf(x3.x, x3.y), fmaxf(x3.z, x3.w)));
        #pragma unroll
        for (int o = 32; o > 0; o >>= 1)
            v = fmaxf(v, __shfl_down(v, o));
        __shared__ float wl[16];
        if (lane == 0) wl[wave] = v;
        __syncthreads();
        if (t == 0) {
            float m = wl[0];
            #pragma unroll
            for (int i = 1; i < 16; ++i) m = fmaxf(m, wl[i]);
            pmax[b] = m;   // plain store — no init required
        }
    } else {
        __shared__ unsigned hist[VV];
        __shared__ unsigned offs[VV];
        __shared__ unsigned wtot[16];
        __shared__ unsigned wexc[16];
        hist[2 * t] = 0u; hist[2 * t + 1] = 0u;
        __syncthreads();
        const int id0 = ids[2 * t], id1 = ids[2 * t + 1];
        atomicAdd(&hist[id0], 1u);
        atomicAdd(&hist[id1], 1u);
        __syncthreads();
        const unsigned h0 = hist[2 * t], h1 = hist[2 * t + 1];
        const unsigned s = h0 + h1;
        unsigned ps = s;
        #pragma unroll
        for (int o = 1; o < 64; o <<= 1) {
            unsigned u = __shfl_up(ps, o);
            if (lane >= o) ps += u;
        }
        if (lane == 63) wtot[wave] = ps;
        __syncthreads();
        if (wave == 0 && lane < 16) {
            unsigned v = wtot[lane];
            unsigned pv = v;
            #pragma unroll
            for (int o = 1; o < 16; o <<= 1) {
                unsigned u = __shfl_up(pv, o);
                if (lane >= o) pv += u;
            }
            wexc[lane] = pv - v;
        }
        __syncthreads();
        const unsigned ex = wexc[wave] + ps - s;
        offs[2 * t]     = ex;
        offs[2 * t + 1] = ex + h0;
        __syncthreads();
        unsigned p0 = atomicAdd(&offs[id0], 1u);
        perm[p0] = 2 * t;     sids[p0] = id0;
        unsigned p1 = atomicAdd(&offs[id1], 1u);
        perm[p1] = 2 * t + 1; sids[p1] = id1;
    }
}

__global__ __launch_bounds__(128) void loss_kernel(
    const float* __restrict__ emb,
    const float* __restrict__ tree, const float* __restrict__ mapd,
    const int* __restrict__ perm, const int* __restrict__ sids,
    const float* __restrict__ pmax,
    double* __restrict__ wsum, unsigned* __restrict__ wcnt,
    unsigned* __restrict__ done, float* __restrict__ out)
{
    const int t = threadIdx.x;

    // Triangular decode: linear block -> (bi, bj), bi <= bj.
    const int L = blockIdx.x;
    int bi = (int)((129.0 - sqrt(16641.0 - 8.0 * (double)L)) * 0.5);
    while (64 * bi - bi * (bi - 1) / 2 > L) --bi;
    while (64 * (bi + 1) - (bi + 1) * bi / 2 <= L) ++bi;
    const int bj = bi + (L - (64 * bi - bi * (bi - 1) / 2));

    __shared__ __align__(16) float Ei[BT][STA];   // [i][dim]
    __shared__ __align__(16) float Ejt[DE][STB];  // [dim][j]
    __shared__ int idi[BT];
    __shared__ int idj[BT];
    __shared__ float wm[2];

    // max partial reduction: loads issued first (no dependencies)
    float pv = fmaxf(pmax[t], pmax[t + 128]);

    // ---- Stage tiles: 128 threads, 4 float4 per side each ----
    {
        const int r  = t & 31;
        const int c0 = (t >> 5) << 4;   // 0,16,32,48
        const int gi = perm[bi * BT + r];
        const int gj = perm[bj * BT + r];
        const float4* pa = (const float4*)(emb + (size_t)gi * DE + c0);
        const float4* pb = (const float4*)(emb + (size_t)gj * DE + c0);
        float4 a0 = pa[0], a1 = pa[1], a2 = pa[2], a3 = pa[3];
        float4 b0 = pb[0], b1 = pb[1], b2 = pb[2], b3 = pb[3];
        *(float4*)&Ei[r][c0 + 0]  = a0;
        *(float4*)&Ei[r][c0 + 4]  = a1;
        *(float4*)&Ei[r][c0 + 8]  = a2;
        *(float4*)&Ei[r][c0 + 12] = a3;
        Ejt[c0 + 0][r]  = b0.x; Ejt[c0 + 1][r]  = b0.y; Ejt[c0 + 2][r]  = b0.z; Ejt[c0 + 3][r]  = b0.w;
        Ejt[c0 + 4][r]  = b1.x; Ejt[c0 + 5][r]  = b1.y; Ejt[c0 + 6][r]  = b1.z; Ejt[c0 + 7][r]  = b1.w;
        Ejt[c0 + 8][r]  = b2.x; Ejt[c0 + 9][r]  = b2.y; Ejt[c0 + 10][r] = b2.z; Ejt[c0 + 11][r] = b2.w;
        Ejt[c0 + 12][r] = b3.x; Ejt[c0 + 13][r] = b3.y; Ejt[c0 + 14][r] = b3.z; Ejt[c0 + 15][r] = b3.w;
        if (t < BT)          idi[t] = sids[bi * BT + t];
        else if (t < 2 * BT) idj[t - BT] = sids[bj * BT + (t - BT)];
    }
    // fold pmax wave-reduce into the same barrier as staging
    #pragma unroll
    for (int o = 32; o > 0; o >>= 1)
        pv = fmaxf(pv, __shfl_down(pv, o));
    if ((t & 63) == 0) wm[t >> 6] = pv;
    __syncthreads();

    const float inv = 1.0f / fmaxf(wm[0], wm[1]);

    const int i0 = (t >> 3) * 2;   // 16 groups x 2 rows
    const int j0 = (t & 7) * 4;    // 8 groups x 4 cols

    float acc[2][4];
    #pragma unroll
    for (int s = 0; s < 2; ++s)
        #pragma unroll
        for (int c = 0; c < 4; ++c) acc[s][c] = 0.0f;

    // unroll 2: proven no-spill regime (full unroll spilled in R2/R3/R4)
    #pragma unroll 2
    for (int k = 0; k < 16; ++k) {
        float4 a0 = *(const float4*)&Ei[i0][4 * k];
        float4 a1 = *(const float4*)&Ei[i0 + 1][4 * k];
        float4 b0 = *(const float4*)&Ejt[4 * k + 0][j0];
        float4 b1 = *(const float4*)&Ejt[4 * k + 1][j0];
        float4 b2 = *(const float4*)&Ejt[4 * k + 2][j0];
        float4 b3 = *(const float4*)&Ejt[4 * k + 3][j0];
        acc[0][0] += fabsf(a0.x - b0.x) + fabsf(a0.y - b1.x) + fabsf(a0.z - b2.x) + fabsf(a0.w - b3.x);
        acc[0][1] += fabsf(a0.x - b0.y) + fabsf(a0.y - b1.y) + fabsf(a0.z - b2.y) + fabsf(a0.w - b3.y);
        acc[0][2] += fabsf(a0.x - b0.z) + fabsf(a0.y - b1.z) + fabsf(a0.z - b2.z) + fabsf(a0.w - b3.z);
        acc[0][3] += fabsf(a0.x - b0.w) + fabsf(a0.y - b1.w) + fabsf(a0.z - b2.w) + fabsf(a0.w - b3.w);
        acc[1][0] += fabsf(a1.x - b0.x) + fabsf(a1.y - b1.x) + fabsf(a1.z - b2.x) + fabsf(a1.w - b3.x);
        acc[1][1] += fabsf(a1.x - b0.y) + fabsf(a1.y - b1.y) + fabsf(a1.z - b2.y) + fabsf(a1.w - b3.y);
        acc[1][2] += fabsf(a1.x - b0.z) + fabsf(a1.y - b1.z) + fabsf(a1.z - b2.z) + fabsf(a1.w - b3.z);
        acc[1][3] += fabsf(a1.x - b0.w) + fabsf(a1.y - b1.w) + fabsf(a1.z - b2.w) + fabsf(a1.w - b3.w);
    }

    // ---- Epilogue: fused metric gather (sorted ids -> L2-local) ----
    float pp = 0.0f;
    unsigned cnt = 0;
    #pragma unroll
    for (int s = 0; s < 2; ++s) {
        const int ia = idi[i0 + s];
        #pragma unroll
        for (int c = 0; c < 4; ++c) {
            const int ja = idj[j0 + c];
            const int off = ia * VV + ja;
            const float metric = (tree[off] + mapd[off] * inv) * 0.5f;
            if (ia != ja) {
                pp += fabsf(acc[s][c] * (1.0f / (float)DE) - metric);
                cnt += 1u;
            }
        }
    }

    #pragma unroll
    for (int o = 32; o > 0; o >>= 1) {
        pp  += __shfl_down(pp, o);
        cnt += __shfl_down(cnt, o);
    }
    __shared__ float    wsum_l[2];
    __shared__ unsigned wcnt_l[2];
    if ((t & 63) == 0) { wsum_l[t >> 6] = pp; wcnt_l[t >> 6] = cnt; }
    __syncthreads();
    if (t == 0) {
        const float    w = (bi == bj) ? 1.0f : 2.0f;
        const unsigned u = (bi == bj) ? 1u : 2u;
        atomicAdd(wsum, (double)((wsum_l[0] + wsum_l[1]) * w));
        atomicAdd(wcnt, (wcnt_l[0] + wcnt_l[1]) * u);
        __threadfence();
        const unsigned old = atomicAdd(done, 1u);
        if (old == (unsigned)NBLK - 1u) {
            const double   S = atomicAdd(wsum, 0.0);
            const unsigned C = atomicAdd(wcnt, 0u);
            out[0] = (float)(S / (double)C);
        }
    }
}

extern "C" void kernel_launch(void* const* d_in, const int* in_sizes, int n_in,
                              void* d_out, int out_size, void* d_ws, size_t ws_size,
                              hipStream_t stream) {
    const int*   ids  = (const int*)d_in[0];
    const float* emb  = (const float*)d_in[1];
    const float* tree = (const float*)d_in[2];
    const float* mapd = (const float*)d_in[3];
    float* out = (float*)d_out;

    double*   wsum = (double*)d_ws;                      // [0:8)
    unsigned* wcnt = (unsigned*)((char*)d_ws + 8);       // [8:12)
    unsigned* done = (unsigned*)((char*)d_ws + 12);      // [12:16)
    float*    pmax = (float*)((char*)d_ws + 16);         // 256 floats
    int*      perm = (int*)((char*)d_ws + 1040);         // 2048 ints
    int*      sids = (int*)((char*)d_ws + 9232);         // 2048 ints

    prep_kernel<<<257, 1024, 0, stream>>>(ids, (const float4*)mapd, pmax,
                                          perm, sids, wsum, wcnt, done);

    loss_kernel<<<NBLK, 128, 0, stream>>>(emb, tree, mapd, perm, sids, pmax,
                                          wsum, wcnt, done, out);
}

// Round 8
// 101.820 us; speedup vs baseline: 1.6492x; 1.6492x over previous
//
#include <hip/hip_runtime.h>
#include <hip/hip_bf16.h>

#define NL 2048   // languages
#define DE 64     // embedding dim
#define VV 2048   // vocab
#define BT 32     // pair tile (32x32)
#define NT (NL / BT)              // 64 tiles per side
#define NBLK (NT * (NT + 1) / 2)  // 2080 triangular tiles
#define STA 68    // Ei stride
#define STB 36    // Ejt stride

// ws layout (no memset needed — every word is written before it is read):
// [0:1024)       float pmax[256]   (plain stores by prep max-blocks)
// [1024:9216)    int   perm[2048]
// [9216:17408)   int   sids[2048]
// [17408:25728)  float psum[2080]  (plain stores by loss blocks)
// [25728:34048)  uint  pcnt[2080]

// Blocks 0..255: block-local max over map_dist slice -> pmax[b] (plain store).
// Block 256: counting-sort 2048 ids in LDS.
__global__ __launch_bounds__(1024) void prep_kernel(const int* __restrict__ ids,
                                                    const float4* __restrict__ m4,
                                                    float* __restrict__ pmax,
                                                    int* __restrict__ perm,
                                                    int* __restrict__ sids) {
    const int t = threadIdx.x;
    const int lane = t & 63, wave = t >> 6;
    const int b = blockIdx.x;

    if (b < 256) {
        const float4* p = m4 + (size_t)b * 4096;
        const float4 x0 = p[t], x1 = p[t + 1024], x2 = p[t + 2048], x3 = p[t + 3072];
        float v = fmaxf(fmaxf(fmaxf(x0.x, x0.y), fmaxf(x0.z, x0.w)),
                        fmaxf(fmaxf(x1.x, x1.y), fmaxf(x1.z, x1.w)));
        v = fmaxf(v, fmaxf(fmaxf(x2.x, x2.y), fmaxf(x2.z, x2.w)));
        v = fmaxf(v, fmaxf(fmaxf(x3.x, x3.y), fmaxf(x3.z, x3.w)));
        #pragma unroll
        for (int o = 32; o > 0; o >>= 1)
            v = fmaxf(v, __shfl_down(v, o));
        __shared__ float wl[16];
        if (lane == 0) wl[wave] = v;
        __syncthreads();
        if (t == 0) {
            float m = wl[0];
            #pragma unroll
            for (int i = 1; i < 16; ++i) m = fmaxf(m, wl[i]);
            pmax[b] = m;   // plain store — no init required
        }
    } else {
        __shared__ unsigned hist[VV];
        __shared__ unsigned offs[VV];
        __shared__ unsigned wtot[16];
        __shared__ unsigned wexc[16];
        hist[2 * t] = 0u; hist[2 * t + 1] = 0u;
        __syncthreads();
        const int id0 = ids[2 * t], id1 = ids[2 * t + 1];
        atomicAdd(&hist[id0], 1u);
        atomicAdd(&hist[id1], 1u);
        __syncthreads();
        const unsigned h0 = hist[2 * t], h1 = hist[2 * t + 1];
        const unsigned s = h0 + h1;
        unsigned ps = s;
        #pragma unroll
        for (int o = 1; o < 64; o <<= 1) {
            unsigned u = __shfl_up(ps, o);
            if (lane >= o) ps += u;
        }
        if (lane == 63) wtot[wave] = ps;
        __syncthreads();
        if (wave == 0 && lane < 16) {
            unsigned v = wtot[lane];
            unsigned pv = v;
            #pragma unroll
            for (int o = 1; o < 16; o <<= 1) {
                unsigned u = __shfl_up(pv, o);
                if (lane >= o) pv += u;
            }
            wexc[lane] = pv - v;
        }
        __syncthreads();
        const unsigned ex = wexc[wave] + ps - s;
        offs[2 * t]     = ex;
        offs[2 * t + 1] = ex + h0;
        __syncthreads();
        unsigned p0 = atomicAdd(&offs[id0], 1u);
        perm[p0] = 2 * t;     sids[p0] = id0;
        unsigned p1 = atomicAdd(&offs[id1], 1u);
        perm[p1] = 2 * t + 1; sids[p1] = id1;
    }
}

__global__ __launch_bounds__(128) void loss_kernel(
    const float* __restrict__ emb,
    const float* __restrict__ tree, const float* __restrict__ mapd,
    const int* __restrict__ perm, const int* __restrict__ sids,
    const float* __restrict__ pmax,
    float* __restrict__ psum, unsigned* __restrict__ pcnt)
{
    const int t = threadIdx.x;

    // Triangular decode (fp32 sqrt; while-loops fix rounding): L -> (bi, bj), bi <= bj
    const int L = blockIdx.x;
    int bi = (int)((129.0f - sqrtf(16641.0f - 8.0f * (float)L)) * 0.5f);
    if (bi > 63) bi = 63;
    while (64 * bi - bi * (bi - 1) / 2 > L) --bi;
    while (64 * (bi + 1) - (bi + 1) * bi / 2 <= L) ++bi;
    const int bj = bi + (L - (64 * bi - bi * (bi - 1) / 2));

    __shared__ __align__(16) float Ei[BT][STA];   // [i][dim]
    __shared__ __align__(16) float Ejt[DE][STB];  // [dim][j]
    __shared__ int idi[BT];
    __shared__ int idj[BT];
    __shared__ float wm[2];

    // max partials: independent loads issued first
    float pv = fmaxf(pmax[t], pmax[t + 128]);

    // ---- Stage tiles: 128 threads, 4 float4 per side each ----
    {
        const int r  = t & 31;
        const int c0 = (t >> 5) << 4;   // 0,16,32,48
        const int gi = perm[bi * BT + r];
        const int gj = perm[bj * BT + r];
        const float4* pa = (const float4*)(emb + (size_t)gi * DE + c0);
        const float4* pb = (const float4*)(emb + (size_t)gj * DE + c0);
        float4 a0 = pa[0], a1 = pa[1], a2 = pa[2], a3 = pa[3];
        float4 b0 = pb[0], b1 = pb[1], b2 = pb[2], b3 = pb[3];
        *(float4*)&Ei[r][c0 + 0]  = a0;
        *(float4*)&Ei[r][c0 + 4]  = a1;
        *(float4*)&Ei[r][c0 + 8]  = a2;
        *(float4*)&Ei[r][c0 + 12] = a3;
        Ejt[c0 + 0][r]  = b0.x; Ejt[c0 + 1][r]  = b0.y; Ejt[c0 + 2][r]  = b0.z; Ejt[c0 + 3][r]  = b0.w;
        Ejt[c0 + 4][r]  = b1.x; Ejt[c0 + 5][r]  = b1.y; Ejt[c0 + 6][r]  = b1.z; Ejt[c0 + 7][r]  = b1.w;
        Ejt[c0 + 8][r]  = b2.x; Ejt[c0 + 9][r]  = b2.y; Ejt[c0 + 10][r] = b2.z; Ejt[c0 + 11][r] = b2.w;
        Ejt[c0 + 12][r] = b3.x; Ejt[c0 + 13][r] = b3.y; Ejt[c0 + 14][r] = b3.z; Ejt[c0 + 15][r] = b3.w;
        if (t < BT)          idi[t] = sids[bi * BT + t];
        else if (t < 2 * BT) idj[t - BT] = sids[bj * BT + (t - BT)];
    }
    #pragma unroll
    for (int o = 32; o > 0; o >>= 1)
        pv = fmaxf(pv, __shfl_down(pv, o));
    if ((t & 63) == 0) wm[t >> 6] = pv;
    __syncthreads();

    const float inv = 1.0f / fmaxf(wm[0], wm[1]);

    const int i0 = (t >> 3) * 2;   // 16 groups x 2 rows
    const int j0 = (t & 7) * 4;    // 8 groups x 4 cols

    float acc[2][4];
    #pragma unroll
    for (int s = 0; s < 2; ++s)
        #pragma unroll
        for (int c = 0; c < 4; ++c) acc[s][c] = 0.0f;

    // unroll 2: proven no-spill regime
    #pragma unroll 2
    for (int k = 0; k < 16; ++k) {
        float4 a0 = *(const float4*)&Ei[i0][4 * k];
        float4 a1 = *(const float4*)&Ei[i0 + 1][4 * k];
        float4 b0 = *(const float4*)&Ejt[4 * k + 0][j0];
        float4 b1 = *(const float4*)&Ejt[4 * k + 1][j0];
        float4 b2 = *(const float4*)&Ejt[4 * k + 2][j0];
        float4 b3 = *(const float4*)&Ejt[4 * k + 3][j0];
        acc[0][0] += fabsf(a0.x - b0.x) + fabsf(a0.y - b1.x) + fabsf(a0.z - b2.x) + fabsf(a0.w - b3.x);
        acc[0][1] += fabsf(a0.x - b0.y) + fabsf(a0.y - b1.y) + fabsf(a0.z - b2.y) + fabsf(a0.w - b3.y);
        acc[0][2] += fabsf(a0.x - b0.z) + fabsf(a0.y - b1.z) + fabsf(a0.z - b2.z) + fabsf(a0.w - b3.z);
        acc[0][3] += fabsf(a0.x - b0.w) + fabsf(a0.y - b1.w) + fabsf(a0.z - b2.w) + fabsf(a0.w - b3.w);
        acc[1][0] += fabsf(a1.x - b0.x) + fabsf(a1.y - b1.x) + fabsf(a1.z - b2.x) + fabsf(a1.w - b3.x);
        acc[1][1] += fabsf(a1.x - b0.y) + fabsf(a1.y - b1.y) + fabsf(a1.z - b2.y) + fabsf(a1.w - b3.y);
        acc[1][2] += fabsf(a1.x - b0.z) + fabsf(a1.y - b1.z) + fabsf(a1.z - b2.z) + fabsf(a1.w - b3.z);
        acc[1][3] += fabsf(a1.x - b0.w) + fabsf(a1.y - b1.w) + fabsf(a1.z - b2.w) + fabsf(a1.w - b3.w);
    }

    // ---- Epilogue: fused metric gather (sorted ids -> L2-local) ----
    float pp = 0.0f;
    unsigned cnt = 0;
    #pragma unroll
    for (int s = 0; s < 2; ++s) {
        const int ia = idi[i0 + s];
        #pragma unroll
        for (int c = 0; c < 4; ++c) {
            const int ja = idj[j0 + c];
            const int off = ia * VV + ja;
            const float metric = (tree[off] + mapd[off] * inv) * 0.5f;
            if (ia != ja) {
                pp += fabsf(acc[s][c] * (1.0f / (float)DE) - metric);
                cnt += 1u;
            }
        }
    }

    #pragma unroll
    for (int o = 32; o > 0; o >>= 1) {
        pp  += __shfl_down(pp, o);
        cnt += __shfl_down(cnt, o);
    }
    __shared__ float    wsum_l[2];
    __shared__ unsigned wcnt_l[2];
    if ((t & 63) == 0) { wsum_l[t >> 6] = pp; wcnt_l[t >> 6] = cnt; }
    __syncthreads();
    if (t == 0) {
        const float    w = (bi == bj) ? 1.0f : 2.0f;
        const unsigned u = (bi == bj) ? 1u : 2u;
        psum[L] = (wsum_l[0] + wsum_l[1]) * w;   // plain stores — NO atomics
        pcnt[L] = (wcnt_l[0] + wcnt_l[1]) * u;
    }
}

__global__ __launch_bounds__(1024) void finalize_kernel(const float* __restrict__ psum,
                                                        const unsigned* __restrict__ pcnt,
                                                        float* __restrict__ out) {
    const int t = threadIdx.x;
    const int lane = t & 63, wave = t >> 6;
    double s = 0.0;
    unsigned c = 0;
    for (int i = t; i < NBLK; i += 1024) { s += (double)psum[i]; c += pcnt[i]; }
    #pragma unroll
    for (int o = 32; o > 0; o >>= 1) {
        s += __shfl_down(s, o);
        c += __shfl_down(c, o);
    }
    __shared__ double   sl[16];
    __shared__ unsigned cl[16];
    if (lane == 0) { sl[wave] = s; cl[wave] = c; }
    __syncthreads();
    if (t == 0) {
        double   S = sl[0];
        unsigned C = cl[0];
        #pragma unroll
        for (int i = 1; i < 16; ++i) { S += sl[i]; C += cl[i]; }
        out[0] = (float)(S / (double)C);
    }
}

extern "C" void kernel_launch(void* const* d_in, const int* in_sizes, int n_in,
                              void* d_out, int out_size, void* d_ws, size_t ws_size,
                              hipStream_t stream) {
    const int*   ids  = (const int*)d_in[0];
    const float* emb  = (const float*)d_in[1];
    const float* tree = (const float*)d_in[2];
    const float* mapd = (const float*)d_in[3];
    float* out = (float*)d_out;

    float*    pmax = (float*)d_ws;                        // 256 floats
    int*      perm = (int*)((char*)d_ws + 1024);          // 2048 ints
    int*      sids = (int*)((char*)d_ws + 9216);          // 2048 ints
    float*    psum = (float*)((char*)d_ws + 17408);       // 2080 floats
    unsigned* pcnt = (unsigned*)((char*)d_ws + 25728);    // 2080 uints

    prep_kernel<<<257, 1024, 0, stream>>>(ids, (const float4*)mapd, pmax, perm, sids);

    loss_kernel<<<NBLK, 128, 0, stream>>>(emb, tree, mapd, perm, sids, pmax, psum, pcnt);

    finalize_kernel<<<1, 1024, 0, stream>>>(psum, pcnt, out);
}